// Round 10
// baseline (13957.103 us; speedup 1.0000x reference)
//
#include <hip/hip_runtime.h>
#include <hip/hip_cooperative_groups.h>
#include <math.h>

namespace cg = cooperative_groups;

#define DMEM   1024
#define NGATES 2048
#define NB     128
#define NT     32
#define STEPN  1048576L

__device__ inline float sigm(float x) { return 1.f / (1.f + __expf(-x)); }

// ---------------------------------------------------------------------------
// gemm128_core: fp32 128x128 tile, BK=16, 256 thr, 8x8/thread, prefetch.
//  FOLD 0: A plain.  FOLD 1: A = P0+P1+abias[k].  rep!=null: A=relu(rep*A)
// ---------------------------------------------------------------------------
template<int FOLD>
__device__ __forceinline__ void gemm128_core(
    const float* __restrict__ A, int lda, long psA,
    const float* __restrict__ abias,
    const float* __restrict__ rep,
    const float* __restrict__ W, int ldw,
    const float* __restrict__ bias,
    float* __restrict__ C, int ldc,
    int row0, int col0, int kbeg, int kend,
    float (*As)[132], float (*Bs)[132])
{
    const int tid  = threadIdx.x;
    const int tr   = (tid >> 4) << 2, tc = (tid & 15) << 2;
    const int arow = tid >> 1, ah = (tid & 1) * 8;
    const int brow = tid >> 4, bcol = (tid & 15) * 8;

    float4 a0, a1, b0, b1;
    auto LOAD = [&](int k0) {
        const float* ap = A + (long)(row0 + arow) * lda + k0 + ah;
        a0 = *(const float4*)ap;
        a1 = *(const float4*)(ap + 4);
        if (FOLD) {
            float4 p0 = *(const float4*)(ap + psA);
            float4 p1 = *(const float4*)(ap + psA + 4);
            float4 c0 = *(const float4*)(abias + k0 + ah);
            float4 c1 = *(const float4*)(abias + k0 + ah + 4);
            a0.x += p0.x + c0.x; a0.y += p0.y + c0.y;
            a0.z += p0.z + c0.z; a0.w += p0.w + c0.w;
            a1.x += p1.x + c1.x; a1.y += p1.y + c1.y;
            a1.z += p1.z + c1.z; a1.w += p1.w + c1.w;
        }
        if (rep) {
            float4 r0 = *(const float4*)(rep + k0 + ah);
            float4 r1 = *(const float4*)(rep + k0 + ah + 4);
            a0.x = fmaxf(a0.x * r0.x, 0.f); a0.y = fmaxf(a0.y * r0.y, 0.f);
            a0.z = fmaxf(a0.z * r0.z, 0.f); a0.w = fmaxf(a0.w * r0.w, 0.f);
            a1.x = fmaxf(a1.x * r1.x, 0.f); a1.y = fmaxf(a1.y * r1.y, 0.f);
            a1.z = fmaxf(a1.z * r1.z, 0.f); a1.w = fmaxf(a1.w * r1.w, 0.f);
        }
        const float* bp = W + (long)(k0 + brow) * ldw + col0 + bcol;
        b0 = *(const float4*)bp;
        b1 = *(const float4*)(bp + 4);
    };

    float acc[8][8] = {};
    LOAD(kbeg);
    const int NIT = (kend - kbeg) >> 4;
    for (int it = 0; it < NIT; ++it) {
        __syncthreads();
        As[ah + 0][arow] = a0.x; As[ah + 1][arow] = a0.y;
        As[ah + 2][arow] = a0.z; As[ah + 3][arow] = a0.w;
        As[ah + 4][arow] = a1.x; As[ah + 5][arow] = a1.y;
        As[ah + 6][arow] = a1.z; As[ah + 7][arow] = a1.w;
        *(float4*)&Bs[brow][bcol]     = b0;
        *(float4*)&Bs[brow][bcol + 4] = b1;
        __syncthreads();
        if (it + 1 < NIT) LOAD(kbeg + ((it + 1) << 4));
#pragma unroll
        for (int kk = 0; kk < 16; ++kk) {
            float a[8], b[8];
            *(float4*)&a[0] = *(const float4*)&As[kk][tr];
            *(float4*)&a[4] = *(const float4*)&As[kk][64 + tr];
            *(float4*)&b[0] = *(const float4*)&Bs[kk][tc];
            *(float4*)&b[4] = *(const float4*)&Bs[kk][64 + tc];
#pragma unroll
            for (int i = 0; i < 8; ++i)
#pragma unroll
                for (int j = 0; j < 8; ++j)
                    acc[i][j] = fmaf(a[i], b[j], acc[i][j]);
        }
    }

#pragma unroll
    for (int jh = 0; jh < 2; ++jh) {
        int cbase = col0 + jh * 64 + tc;
        float4 bv = make_float4(0.f, 0.f, 0.f, 0.f);
        if (bias) bv = *(const float4*)&bias[cbase];
#pragma unroll
        for (int ih = 0; ih < 2; ++ih) {
#pragma unroll
            for (int i = 0; i < 4; ++i) {
                int row = row0 + ih * 64 + tr + i;
                *(float4*)(C + (long)row * ldc + cbase) =
                    make_float4(acc[ih * 4 + i][jh * 4 + 0] + bv.x,
                                acc[ih * 4 + i][jh * 4 + 1] + bv.y,
                                acc[ih * 4 + i][jh * 4 + 2] + bv.z,
                                acc[ih * 4 + i][jh * 4 + 3] + bv.w);
            }
        }
    }
}

// ---------------------------------------------------------------------------
// phase A launch 1: inpP[kc] = x @ Wi partials (split-K2, 512 blocks = 2/CU)
// ---------------------------------------------------------------------------
__global__ __launch_bounds__(256)
void gemm_inp(const float* __restrict__ x, const float* __restrict__ Wi,
              float* __restrict__ inpP)
{
    __shared__ float As[16][132];
    __shared__ float Bs[16][132];
    const int bid = blockIdx.x;
    const int kc = bid >> 8, j = bid & 255;
    gemm128_core<0>(x, 1024, 0, nullptr, nullptr, Wi, 1024, nullptr,
                    inpP + (long)kc * 4194304, 1024,
                    (j >> 3) * 128, (j & 7) * 128, kc * 512, kc * 512 + 512,
                    As, Bs);
}

// ---------------------------------------------------------------------------
// phase A launch 2 (768 blocks = 3/CU), one core call site:
//   bid<256:  v  = (P0+P1+bi) @ Wv + bv
//   bid>=256: gi = relu(rep*(P0+P1+bi)) @ Wg + bg
// ---------------------------------------------------------------------------
__global__ __launch_bounds__(256)
void vgi_kern(const float* __restrict__ inpP, const float* __restrict__ bi,
              const float* __restrict__ repw,
              const float* __restrict__ Wv, const float* __restrict__ bv,
              float* __restrict__ v,
              const float* __restrict__ Wg, const float* __restrict__ bg,
              float* __restrict__ gi)
{
    __shared__ float As[16][132];
    __shared__ float Bs[16][132];
    const int bid = blockIdx.x;
    const bool isv = bid < 256;
    const int  j   = isv ? bid : bid - 256;
    const int  row0 = isv ? (j >> 3) * 128 : (j >> 4) * 128;
    const int  col0 = isv ? (j & 7) * 128  : (j & 15) * 128;
    gemm128_core<1>(inpP, 1024, 4194304, bi,
                    isv ? nullptr : repw,
                    isv ? Wv : Wg, isv ? 1024 : 2048,
                    isv ? bv : bg,
                    isv ? v : gi, isv ? 1024 : 2048,
                    row0, col0, 0, 1024, As, Bs);
}

// ---------------------------------------------------------------------------
// gemm64_core: 64x64 tile, BK=32, 4x4/thread, single LDS buffer + prefetch.
// AMODE 0: plain A.  AMODE 1: A = relu(P0+P1+abias)
// ---------------------------------------------------------------------------
template<int AMODE>
__device__ __forceinline__ void gemm64_core(
    const float* __restrict__ A, int lda, long psA,
    const float* __restrict__ abias,
    const float* __restrict__ W, int ldw,
    float* __restrict__ C, int ldc,
    int row0, int col0, int kbeg, int kend,
    float (*As)[68], float (*Bs)[68])
{
    const int tid  = threadIdx.x;
    const int tr   = (tid >> 4) << 2, tc = (tid & 15) << 2;
    const int arow = tid >> 2, aseg = (tid & 3) * 8;
    const int brow = tid >> 3, bcol = (tid & 7) * 8;

    float4 a0, a1, b0, b1;
    auto LOAD = [&](int k0) {
        const float* ap = A + (long)(row0 + arow) * lda + k0 + aseg;
        if (AMODE == 0) {
            a0 = *(const float4*)ap;
            a1 = *(const float4*)(ap + 4);
        } else {
            float4 p0 = *(const float4*)ap;
            float4 p1 = *(const float4*)(ap + psA);
            float4 q0 = *(const float4*)(ap + 4);
            float4 q1 = *(const float4*)(ap + psA + 4);
            float4 c0 = *(const float4*)(abias + k0 + aseg);
            float4 c1 = *(const float4*)(abias + k0 + aseg + 4);
            a0.x = fmaxf(p0.x + p1.x + c0.x, 0.f);
            a0.y = fmaxf(p0.y + p1.y + c0.y, 0.f);
            a0.z = fmaxf(p0.z + p1.z + c0.z, 0.f);
            a0.w = fmaxf(p0.w + p1.w + c0.w, 0.f);
            a1.x = fmaxf(q0.x + q1.x + c1.x, 0.f);
            a1.y = fmaxf(q0.y + q1.y + c1.y, 0.f);
            a1.z = fmaxf(q0.z + q1.z + c1.z, 0.f);
            a1.w = fmaxf(q0.w + q1.w + c1.w, 0.f);
        }
        const float* bp = W + (long)(k0 + brow) * ldw + col0 + bcol;
        b0 = *(const float4*)bp;
        b1 = *(const float4*)(bp + 4);
    };

    float acc[4][4] = {};
    LOAD(kbeg);
    const int NIT = (kend - kbeg) >> 5;
    for (int it = 0; it < NIT; ++it) {
        __syncthreads();
        As[aseg + 0][arow] = a0.x; As[aseg + 1][arow] = a0.y;
        As[aseg + 2][arow] = a0.z; As[aseg + 3][arow] = a0.w;
        As[aseg + 4][arow] = a1.x; As[aseg + 5][arow] = a1.y;
        As[aseg + 6][arow] = a1.z; As[aseg + 7][arow] = a1.w;
        *(float4*)&Bs[brow][bcol]     = b0;
        *(float4*)&Bs[brow][bcol + 4] = b1;
        __syncthreads();
        if (it + 1 < NIT) LOAD(kbeg + ((it + 1) << 5));
#pragma unroll
        for (int kk = 0; kk < 32; ++kk) {
            float4 av = *(const float4*)&As[kk][tr];
            float4 bv = *(const float4*)&Bs[kk][tc];
            acc[0][0] = fmaf(av.x, bv.x, acc[0][0]); acc[0][1] = fmaf(av.x, bv.y, acc[0][1]);
            acc[0][2] = fmaf(av.x, bv.z, acc[0][2]); acc[0][3] = fmaf(av.x, bv.w, acc[0][3]);
            acc[1][0] = fmaf(av.y, bv.x, acc[1][0]); acc[1][1] = fmaf(av.y, bv.y, acc[1][1]);
            acc[1][2] = fmaf(av.y, bv.z, acc[1][2]); acc[1][3] = fmaf(av.y, bv.w, acc[1][3]);
            acc[2][0] = fmaf(av.z, bv.x, acc[2][0]); acc[2][1] = fmaf(av.z, bv.y, acc[2][1]);
            acc[2][2] = fmaf(av.z, bv.z, acc[2][2]); acc[2][3] = fmaf(av.z, bv.w, acc[2][3]);
            acc[3][0] = fmaf(av.w, bv.x, acc[3][0]); acc[3][1] = fmaf(av.w, bv.y, acc[3][1]);
            acc[3][2] = fmaf(av.w, bv.z, acc[3][2]); acc[3][3] = fmaf(av.w, bv.w, acc[3][3]);
        }
    }

#pragma unroll
    for (int i = 0; i < 4; ++i)
        *(float4*)(C + (long)(row0 + tr + i) * ldc + col0 + tc) =
            make_float4(acc[i][0], acc[i][1], acc[i][2], acc[i][3]);
}

// ---------------------------------------------------------------------------
// block reduction (256 threads) of (sum, sumsq); safe for repeated use
// ---------------------------------------------------------------------------
__device__ inline void block_reduce2(float& s1, float& s2)
{
    __shared__ float red[2][4];
    __syncthreads();
#pragma unroll
    for (int off = 32; off > 0; off >>= 1) {
        s1 += __shfl_down(s1, off, 64);
        s2 += __shfl_down(s2, off, 64);
    }
    int tid = threadIdx.x;
    if ((tid & 63) == 0) { red[0][tid >> 6] = s1; red[1][tid >> 6] = s2; }
    __syncthreads();
    s1 = red[0][0] + red[0][1] + red[0][2] + red[0][3];
    s2 = red[1][0] + red[1][1] + red[1][2] + red[1][3];
}

// ---------------------------------------------------------------------------
// ln1 (t=0): m1 = LN(mem0 + v[:,0])*g+b ; tm = tanh(mem0)
// ---------------------------------------------------------------------------
__global__ __launch_bounds__(256)
void ln1_kern(const float* __restrict__ memprev, const float* __restrict__ v,
              const float* __restrict__ g, const float* __restrict__ bb,
              float* __restrict__ m1, float* __restrict__ tm)
{
    const int row = blockIdx.x;
    const int b   = row >> 3;
    const int d   = threadIdx.x << 2;

    float4 mv = *(const float4*)(memprev + (long)row * DMEM + d);
    float4 vv = *(const float4*)(v + ((long)b * NT) * DMEM + d);

    *(float4*)(tm + (long)row * DMEM + d) =
        make_float4(tanhf(mv.x), tanhf(mv.y), tanhf(mv.z), tanhf(mv.w));

    float x0 = mv.x + vv.x, x1 = mv.y + vv.y, x2 = mv.z + vv.z, x3 = mv.w + vv.w;
    float s1 = x0 + x1 + x2 + x3;
    float s2 = x0 * x0 + x1 * x1 + x2 * x2 + x3 * x3;
    block_reduce2(s1, s2);
    float mean = s1 * (1.f / 1024.f);
    float var  = s2 * (1.f / 1024.f) - mean * mean;
    float inv  = 1.f / sqrtf(var + 1e-5f);

    float4 gg = *(const float4*)&g[d];
    float4 bv = *(const float4*)&bb[d];
    *(float4*)(m1 + (long)row * DMEM + d) =
        make_float4((x0 - mean) * inv * gg.x + bv.x,
                    (x1 - mean) * inv * gg.y + bv.y,
                    (x2 - mean) * inv * gg.z + bv.z,
                    (x3 - mean) * inv * gg.w + bv.w);
}

// ---------------------------------------------------------------------------
// tail row: h2=relu(h2P0+h2P1+bm); t2=tanh(LN2(m1+h2));
// out = sig(gm+gi+ib)*t2 + sig(gm'+gi'+fb)*mem;
// if !last: tm=tanh(out); m1'=LN1(out+v[:,t+1]);  if last: also final_mem.
// ---------------------------------------------------------------------------
__device__ __forceinline__ void tail_row(
    int row, int t, const float* __restrict__ m1in,
    const float* __restrict__ h2P, const float* __restrict__ bm,
    const float* __restrict__ g2, const float* __restrict__ b2,
    const float* __restrict__ gm, const float* __restrict__ gi,
    const float* __restrict__ memprev, float fb, float ib,
    const float* __restrict__ v,
    const float* __restrict__ g1, const float* __restrict__ b1,
    float* __restrict__ outp, float* m1out, float* __restrict__ tm,
    int last, float* __restrict__ outFinal)
{
    const int b = row >> 3;
    const int d = threadIdx.x << 2;
    const long o = (long)row * DMEM + d;

    float4 a  = *(const float4*)(m1in + o);
    float4 q0 = *(const float4*)(h2P + o);
    float4 q1 = *(const float4*)(h2P + 1048576 + o);
    float4 bb = *(const float4*)&bm[d];
    float x0 = a.x + fmaxf(q0.x + q1.x + bb.x, 0.f);
    float x1 = a.y + fmaxf(q0.y + q1.y + bb.y, 0.f);
    float x2 = a.z + fmaxf(q0.z + q1.z + bb.z, 0.f);
    float x3 = a.w + fmaxf(q0.w + q1.w + bb.w, 0.f);

    float s1 = x0 + x1 + x2 + x3;
    float s2 = x0 * x0 + x1 * x1 + x2 * x2 + x3 * x3;
    block_reduce2(s1, s2);
    float mean = s1 * (1.f / 1024.f);
    float var  = s2 * (1.f / 1024.f) - mean * mean;
    float inv  = 1.f / sqrtf(var + 1e-5f);

    float4 gg  = *(const float4*)&g2[d];
    float4 b2v = *(const float4*)&b2[d];
    float t20 = tanhf((x0 - mean) * inv * gg.x + b2v.x);
    float t21 = tanhf((x1 - mean) * inv * gg.y + b2v.y);
    float t22 = tanhf((x2 - mean) * inv * gg.z + b2v.z);
    float t23 = tanhf((x3 - mean) * inv * gg.w + b2v.w);

    const long go = (long)row * NGATES + d;
    float4 ge0 = *(const float4*)(gm + go);
    float4 ge1 = *(const float4*)(gm + go + DMEM);
    const long io = ((long)b * NT + t) * NGATES + d;
    float4 i0 = *(const float4*)(gi + io);
    float4 i1 = *(const float4*)(gi + io + DMEM);
    float4 mv = *(const float4*)(memprev + o);

    float4 ov;
    ov.x = sigm(ge0.x + i0.x + ib) * t20 + sigm(ge1.x + i1.x + fb) * mv.x;
    ov.y = sigm(ge0.y + i0.y + ib) * t21 + sigm(ge1.y + i1.y + fb) * mv.y;
    ov.z = sigm(ge0.z + i0.z + ib) * t22 + sigm(ge1.z + i1.z + fb) * mv.z;
    ov.w = sigm(ge0.w + i0.w + ib) * t23 + sigm(ge1.w + i1.w + fb) * mv.w;
    *(float4*)(outp + o) = ov;

    if (!last) {
        float4 vv = *(const float4*)(v + ((long)b * NT + t + 1) * DMEM + d);
        *(float4*)(tm + o) =
            make_float4(tanhf(ov.x), tanhf(ov.y), tanhf(ov.z), tanhf(ov.w));

        float y0 = ov.x + vv.x, y1 = ov.y + vv.y;
        float y2 = ov.z + vv.z, y3 = ov.w + vv.w;
        float u1 = y0 + y1 + y2 + y3;
        float u2 = y0 * y0 + y1 * y1 + y2 * y2 + y3 * y3;
        block_reduce2(u1, u2);
        float mean1 = u1 * (1.f / 1024.f);
        float var1  = u2 * (1.f / 1024.f) - mean1 * mean1;
        float inv1  = 1.f / sqrtf(var1 + 1e-5f);

        float4 g1v = *(const float4*)&g1[d];
        float4 b1v = *(const float4*)&b1[d];
        *(float4*)(m1out + o) =
            make_float4((y0 - mean1) * inv1 * g1v.x + b1v.x,
                        (y1 - mean1) * inv1 * g1v.y + b1v.y,
                        (y2 - mean1) * inv1 * g1v.z + b1v.z,
                        (y3 - mean1) * inv1 * g1v.w + b1v.w);
    } else {
        *(float4*)(outFinal + o) = ov;   // final_mem = outs[31]
    }
}

// ---------------------------------------------------------------------------
// cooperative scan kernel: whole 32-step recurrence, 768 blocks x 256 thr.
// __launch_bounds__(256,3) pins VGPR so 3 blocks/CU co-residency holds
// (r9 failure: unbounded VGPR -> 2 blocks/CU -> coop grid 768 rejected).
// ---------------------------------------------------------------------------
__global__ __launch_bounds__(256, 3)
void scan_kern(const float* __restrict__ mem0,
               const float* __restrict__ Wm,
               const float* __restrict__ bm,
               const float* __restrict__ Wmg,
               float* __restrict__ hP, float* __restrict__ h2P,
               float* __restrict__ gm, float* __restrict__ m1,
               float* __restrict__ tm,
               const float* __restrict__ v,
               const float* __restrict__ gi,
               const float* __restrict__ ln1g,
               const float* __restrict__ ln1b,
               const float* __restrict__ ln2g,
               const float* __restrict__ ln2b,
               const float* __restrict__ fbp,
               const float* __restrict__ ibp,
               float* __restrict__ out)
{
    cg::grid_group grid = cg::this_grid();
    __shared__ float As[32][68];
    __shared__ float Bs[32][68];
    const int bid = blockIdx.x;
    const float fb = *fbp, ib = *ibp;

    for (int t = 0; t < NT; ++t) {
        const float* memprev = (t == 0) ? mem0 : out + (long)(t - 1) * STEPN;

        // ---- L1: h1 partials (split-K2) || gm cols [0,1024) — one call site
        {
            const float* A; int lda; const float* W; int ldw;
            float* C; int ldc; int r0, c0, kb, ke;
            if (bid < 512) {
                int x = bid & 15, y = (bid >> 4) & 15, kc = bid >> 8;
                A = m1; lda = 1024; W = Wm; ldw = 1024;
                C = hP + (long)kc * 1048576; ldc = 1024;
                r0 = y * 64; c0 = x * 64; kb = kc * 512; ke = kb + 512;
            } else {
                int j = bid - 512;
                int x = j & 15, y = (j >> 4) & 1, s = j >> 5;
                A = tm + s * 1024; lda = 8192;
                W = Wmg + (long)s * 2097152; ldw = 2048;
                C = gm + s * 2048; ldc = 16384;
                r0 = y * 64; c0 = x * 64; kb = 0; ke = 1024;
            }
            gemm64_core<0>(A, lda, 0, nullptr, W, ldw, C, ldc,
                           r0, c0, kb, ke, As, Bs);
        }
        grid.sync();

        // ---- L2: h2 partials (fold hP) || gm cols [1024,2048)
        if (bid < 512) {
            int x = bid & 15, y = (bid >> 4) & 15, kc = bid >> 8;
            gemm64_core<1>(hP, 1024, 1048576, bm, Wm, 1024,
                           h2P + (long)kc * 1048576, 1024,
                           y * 64, x * 64, kc * 512, kc * 512 + 512, As, Bs);
        } else {
            int j = bid - 512;
            int x = (j & 15) + 16, y = (j >> 4) & 1, s = j >> 5;
            gemm64_core<0>(tm + s * 1024, 8192, 0, nullptr,
                           Wmg + (long)s * 2097152, 2048,
                           gm + s * 2048, 16384,
                           y * 64, x * 64, 0, 1024, As, Bs);
        }
        grid.sync();

        // ---- tail: 1024 rows over 768 blocks (blocks 0..255 take 2 rows)
        const int last = (t == NT - 1) ? 1 : 0;
        for (int row = bid; row < 1024; row += 768)
            tail_row(row, t, m1, h2P, bm, ln2g, ln2b, gm, gi, memprev,
                     fb, ib, v, ln1g, ln1b, out + (long)t * STEPN, m1, tm,
                     last, out + (long)NT * STEPN);
        grid.sync();
    }
}

// ---------------------------------------------------------------------------
// fallback per-step kernels (r8, proven 5283 us) — used if coop launch fails
// ---------------------------------------------------------------------------
template<int LVL>
__global__ __launch_bounds__(256)
void step_gemms(const float* __restrict__ m1, const float* __restrict__ Wm,
                const float* __restrict__ bm,
                float* __restrict__ hP, float* __restrict__ h2P,
                const float* __restrict__ tm, const float* __restrict__ Wmg,
                float* __restrict__ gm)
{
    __shared__ float As[32][68];
    __shared__ float Bs[32][68];
    const int bid = blockIdx.x;
    if (bid < 512) {
        int x = bid & 15, y = (bid >> 4) & 15, kc = bid >> 8;
        if (LVL == 0)
            gemm64_core<0>(m1, 1024, 0, nullptr, Wm, 1024,
                           hP + (long)kc * 1048576, 1024,
                           y * 64, x * 64, kc * 512, kc * 512 + 512, As, Bs);
        else
            gemm64_core<1>(hP, 1024, 1048576, bm, Wm, 1024,
                           h2P + (long)kc * 1048576, 1024,
                           y * 64, x * 64, kc * 512, kc * 512 + 512, As, Bs);
    } else {
        int j = bid - 512;
        int x = (j & 15) + (LVL == 0 ? 0 : 16);
        int y = (j >> 4) & 1, s = j >> 5;
        gemm64_core<0>(tm + s * 1024, 8192, 0, nullptr,
                       Wmg + (long)s * 2097152, 2048,
                       gm + s * 2048, 16384,
                       y * 64, x * 64, 0, 1024, As, Bs);
    }
}

__global__ __launch_bounds__(256)
void step_fused(const float* m1in, const float* __restrict__ h2P,
                const float* __restrict__ bm,
                const float* __restrict__ g2, const float* __restrict__ b2,
                const float* __restrict__ gm, const float* __restrict__ gi, int t,
                const float* __restrict__ memprev,
                const float* __restrict__ fbp, const float* __restrict__ ibp,
                const float* __restrict__ v,
                const float* __restrict__ g1, const float* __restrict__ b1,
                float* __restrict__ outp, float* m1out,
                float* __restrict__ tm, int last, float* __restrict__ outFinal)
{
    tail_row(blockIdx.x, t, m1in, h2P, bm, g2, b2, gm, gi, memprev,
             *fbp, *ibp, v, g1, b1, outp, m1out, tm, last, outFinal);
}

// ---------------------------------------------------------------------------
extern "C" void kernel_launch(void* const* d_in, const int* in_sizes, int n_in,
                              void* d_out, int out_size, void* d_ws, size_t ws_size,
                              hipStream_t stream)
{
    const float* x    = (const float*)d_in[0];
    const float* mem0 = (const float*)d_in[1];
    const float* Wi   = (const float*)d_in[2];
    const float* bi   = (const float*)d_in[3];
    // d_in[4..7] = Wq,bq,Wk,bk : dead (softmax over singleton axis == 1)
    const float* Wv   = (const float*)d_in[8];
    const float* bv   = (const float*)d_in[9];
    const float* Wm   = (const float*)d_in[10];
    const float* bm   = (const float*)d_in[11];
    const float* ln1g = (const float*)d_in[12];
    const float* ln1b = (const float*)d_in[13];
    const float* ln2g = (const float*)d_in[14];
    const float* ln2b = (const float*)d_in[15];
    const float* repw = (const float*)d_in[16];
    const float* Wg   = (const float*)d_in[17];
    const float* bg   = (const float*)d_in[18];
    const float* Wmg  = (const float*)d_in[19];
    const float* fbp  = (const float*)d_in[20];
    const float* ibp  = (const float*)d_in[21];

    float* out = (float*)d_out;
    char*  ws  = (char*)d_ws;
    const long MB = 1024L * 1024L;

    // persistent across scan
    float* v    = (float*)(ws + 0 * MB);   // 16 MB [4096][1024]
    float* gi   = (float*)(ws + 16 * MB);  // 32 MB [4096][2048]
    // phase-A transient (folded inside vgi_kern's A-staging)
    float* inpP = (float*)(ws + 48 * MB);  // 32 MB [2][4096][1024]
    // per-step
    float* m1   = (float*)(ws + 48 * MB);  //  4 MB
    float* tm   = (float*)(ws + 52 * MB);  //  4 MB
    float* hP   = (float*)(ws + 56 * MB);  //  8 MB [2][1024][1024]
    float* gm   = (float*)(ws + 64 * MB);  //  8 MB [128][8][2048]
    float* h2P  = (float*)(ws + 72 * MB);  //  8 MB [2][1024][1024]
    // peak exactly 80 MB

    dim3 blk(256);

    // ---- phase A ----
    gemm_inp<<<512, blk, 0, stream>>>(x, Wi, inpP);
    vgi_kern<<<768, blk, 0, stream>>>(inpP, bi, repw, Wv, bv, v, Wg, bg, gi);

    // ---- t=0 LN1 + tanh(mem0) ----
    ln1_kern<<<1024, blk, 0, stream>>>(mem0, v, ln1g, ln1b, m1, tm);

    // ---- cooperative scan; fall back to per-step launches on any error ----
    void* args[] = {
        (void*)&mem0, (void*)&Wm, (void*)&bm, (void*)&Wmg,
        (void*)&hP, (void*)&h2P, (void*)&gm, (void*)&m1, (void*)&tm,
        (void*)&v, (void*)&gi,
        (void*)&ln1g, (void*)&ln1b, (void*)&ln2g, (void*)&ln2b,
        (void*)&fbp, (void*)&ibp, (void*)&out
    };
    hipError_t cerr = hipLaunchCooperativeKernel((void*)scan_kern, dim3(768),
                                                 dim3(256), args, 0, stream);
    if (cerr != hipSuccess) {
        (void)hipGetLastError();   // clear sticky error, use fallback path
        for (int t = 0; t < NT; ++t) {
            const float* memprev = (t == 0) ? mem0 : out + (long)(t - 1) * STEPN;
            step_gemms<0><<<768, blk, 0, stream>>>(m1, Wm, bm, hP, h2P, tm, Wmg, gm);
            step_gemms<1><<<768, blk, 0, stream>>>(m1, Wm, bm, hP, h2P, tm, Wmg, gm);
            step_fused<<<1024, blk, 0, stream>>>(
                m1, h2P, bm, ln2g, ln2b, gm, gi, t, memprev, fbp, ibp,
                v, ln1g, ln1b, out + (long)t * STEPN, m1, tm,
                (t == NT - 1) ? 1 : 0, out + (long)NT * STEPN);
        }
    }
}

// Round 11
// 5270.899 us; speedup vs baseline: 2.6480x; 2.6480x over previous
//
#include <hip/hip_runtime.h>
#include <math.h>

#define DMEM   1024
#define NGATES 2048
#define NB     128
#define NT     32
#define STEPN  1048576L

__device__ inline float sigm(float x) { return 1.f / (1.f + __expf(-x)); }

// ---------------------------------------------------------------------------
// gemm128_core: fp32 128x128 tile, BK=16, 256 thr, 8x8/thread, prefetch.
//  FOLD 0: A plain.  FOLD 1: A = P0+P1+abias[k].  rep!=null: A=relu(rep*A)
// ---------------------------------------------------------------------------
template<int FOLD>
__device__ __forceinline__ void gemm128_core(
    const float* __restrict__ A, int lda, long psA,
    const float* __restrict__ abias,
    const float* __restrict__ rep,
    const float* __restrict__ W, int ldw,
    const float* __restrict__ bias,
    float* __restrict__ C, int ldc,
    int row0, int col0, int kbeg, int kend,
    float (*As)[132], float (*Bs)[132])
{
    const int tid  = threadIdx.x;
    const int tr   = (tid >> 4) << 2, tc = (tid & 15) << 2;
    const int arow = tid >> 1, ah = (tid & 1) * 8;
    const int brow = tid >> 4, bcol = (tid & 15) * 8;

    float4 a0, a1, b0, b1;
    auto LOAD = [&](int k0) {
        const float* ap = A + (long)(row0 + arow) * lda + k0 + ah;
        a0 = *(const float4*)ap;
        a1 = *(const float4*)(ap + 4);
        if (FOLD) {
            float4 p0 = *(const float4*)(ap + psA);
            float4 p1 = *(const float4*)(ap + psA + 4);
            float4 c0 = *(const float4*)(abias + k0 + ah);
            float4 c1 = *(const float4*)(abias + k0 + ah + 4);
            a0.x += p0.x + c0.x; a0.y += p0.y + c0.y;
            a0.z += p0.z + c0.z; a0.w += p0.w + c0.w;
            a1.x += p1.x + c1.x; a1.y += p1.y + c1.y;
            a1.z += p1.z + c1.z; a1.w += p1.w + c1.w;
        }
        if (rep) {   // wave-uniform runtime branch (single code path)
            float4 r0 = *(const float4*)(rep + k0 + ah);
            float4 r1 = *(const float4*)(rep + k0 + ah + 4);
            a0.x = fmaxf(a0.x * r0.x, 0.f); a0.y = fmaxf(a0.y * r0.y, 0.f);
            a0.z = fmaxf(a0.z * r0.z, 0.f); a0.w = fmaxf(a0.w * r0.w, 0.f);
            a1.x = fmaxf(a1.x * r1.x, 0.f); a1.y = fmaxf(a1.y * r1.y, 0.f);
            a1.z = fmaxf(a1.z * r1.z, 0.f); a1.w = fmaxf(a1.w * r1.w, 0.f);
        }
        const float* bp = W + (long)(k0 + brow) * ldw + col0 + bcol;
        b0 = *(const float4*)bp;
        b1 = *(const float4*)(bp + 4);
    };

    float acc[8][8] = {};
    LOAD(kbeg);
    const int NIT = (kend - kbeg) >> 4;
    for (int it = 0; it < NIT; ++it) {
        __syncthreads();
        As[ah + 0][arow] = a0.x; As[ah + 1][arow] = a0.y;
        As[ah + 2][arow] = a0.z; As[ah + 3][arow] = a0.w;
        As[ah + 4][arow] = a1.x; As[ah + 5][arow] = a1.y;
        As[ah + 6][arow] = a1.z; As[ah + 7][arow] = a1.w;
        *(float4*)&Bs[brow][bcol]     = b0;
        *(float4*)&Bs[brow][bcol + 4] = b1;
        __syncthreads();
        if (it + 1 < NIT) LOAD(kbeg + ((it + 1) << 4));
#pragma unroll
        for (int kk = 0; kk < 16; ++kk) {
            float a[8], b[8];
            *(float4*)&a[0] = *(const float4*)&As[kk][tr];
            *(float4*)&a[4] = *(const float4*)&As[kk][64 + tr];
            *(float4*)&b[0] = *(const float4*)&Bs[kk][tc];
            *(float4*)&b[4] = *(const float4*)&Bs[kk][64 + tc];
#pragma unroll
            for (int i = 0; i < 8; ++i)
#pragma unroll
                for (int j = 0; j < 8; ++j)
                    acc[i][j] = fmaf(a[i], b[j], acc[i][j]);
        }
    }

#pragma unroll
    for (int jh = 0; jh < 2; ++jh) {
        int cbase = col0 + jh * 64 + tc;
        float4 bv = make_float4(0.f, 0.f, 0.f, 0.f);
        if (bias) bv = *(const float4*)&bias[cbase];
#pragma unroll
        for (int ih = 0; ih < 2; ++ih) {
#pragma unroll
            for (int i = 0; i < 4; ++i) {
                int row = row0 + ih * 64 + tr + i;
                *(float4*)(C + (long)row * ldc + cbase) =
                    make_float4(acc[ih * 4 + i][jh * 4 + 0] + bv.x,
                                acc[ih * 4 + i][jh * 4 + 1] + bv.y,
                                acc[ih * 4 + i][jh * 4 + 2] + bv.z,
                                acc[ih * 4 + i][jh * 4 + 3] + bv.w);
            }
        }
    }
}

// ---------------------------------------------------------------------------
// phase A launch 1: inpP[kc] = x @ Wi partials (split-K2, 512 blocks = 2/CU)
// ---------------------------------------------------------------------------
__global__ __launch_bounds__(256)
void gemm_inp(const float* __restrict__ x, const float* __restrict__ Wi,
              float* __restrict__ inpP)
{
    __shared__ float As[16][132];
    __shared__ float Bs[16][132];
    const int bid = blockIdx.x;
    const int kc = bid >> 8, j = bid & 255;
    gemm128_core<0>(x, 1024, 0, nullptr, nullptr, Wi, 1024, nullptr,
                    inpP + (long)kc * 4194304, 1024,
                    (j >> 3) * 128, (j & 7) * 128, kc * 512, kc * 512 + 512,
                    As, Bs);
}

// ---------------------------------------------------------------------------
// phase A launch 2 (768 blocks = 3/CU), one core call site:
//   bid<256:  v  = (P0+P1+bi) @ Wv + bv
//   bid>=256: gi = relu(rep*(P0+P1+bi)) @ Wg + bg
// ---------------------------------------------------------------------------
__global__ __launch_bounds__(256)
void vgi_kern(const float* __restrict__ inpP, const float* __restrict__ bi,
              const float* __restrict__ repw,
              const float* __restrict__ Wv, const float* __restrict__ bv,
              float* __restrict__ v,
              const float* __restrict__ Wg, const float* __restrict__ bg,
              float* __restrict__ gi)
{
    __shared__ float As[16][132];
    __shared__ float Bs[16][132];
    const int bid = blockIdx.x;
    const bool isv = bid < 256;
    const int  j   = isv ? bid : bid - 256;
    const int  row0 = isv ? (j >> 3) * 128 : (j >> 4) * 128;
    const int  col0 = isv ? (j & 7) * 128  : (j & 15) * 128;
    gemm128_core<1>(inpP, 1024, 4194304, bi,
                    isv ? nullptr : repw,
                    isv ? Wv : Wg, isv ? 1024 : 2048,
                    isv ? bv : bg,
                    isv ? v : gi, isv ? 1024 : 2048,
                    row0, col0, 0, 1024, As, Bs);
}

// ---------------------------------------------------------------------------
// gemm64_core: 64x64 tile, BK=32, 4x4/thread, single LDS buffer + prefetch.
// AMODE 0: plain A.  AMODE 1: A = relu(P0+P1+abias)
// ---------------------------------------------------------------------------
template<int AMODE>
__device__ __forceinline__ void gemm64_core(
    const float* __restrict__ A, int lda, long psA,
    const float* __restrict__ abias,
    const float* __restrict__ W, int ldw,
    float* __restrict__ C, int ldc,
    int row0, int col0, int kbeg, int kend,
    float (*As)[68], float (*Bs)[68])
{
    const int tid  = threadIdx.x;
    const int tr   = (tid >> 4) << 2, tc = (tid & 15) << 2;
    const int arow = tid >> 2, aseg = (tid & 3) * 8;
    const int brow = tid >> 3, bcol = (tid & 7) * 8;

    float4 a0, a1, b0, b1;
    auto LOAD = [&](int k0) {
        const float* ap = A + (long)(row0 + arow) * lda + k0 + aseg;
        if (AMODE == 0) {
            a0 = *(const float4*)ap;
            a1 = *(const float4*)(ap + 4);
        } else {
            float4 p0 = *(const float4*)ap;
            float4 p1 = *(const float4*)(ap + psA);
            float4 q0 = *(const float4*)(ap + 4);
            float4 q1 = *(const float4*)(ap + psA + 4);
            float4 c0 = *(const float4*)(abias + k0 + aseg);
            float4 c1 = *(const float4*)(abias + k0 + aseg + 4);
            a0.x = fmaxf(p0.x + p1.x + c0.x, 0.f);
            a0.y = fmaxf(p0.y + p1.y + c0.y, 0.f);
            a0.z = fmaxf(p0.z + p1.z + c0.z, 0.f);
            a0.w = fmaxf(p0.w + p1.w + c0.w, 0.f);
            a1.x = fmaxf(q0.x + q1.x + c1.x, 0.f);
            a1.y = fmaxf(q0.y + q1.y + c1.y, 0.f);
            a1.z = fmaxf(q0.z + q1.z + c1.z, 0.f);
            a1.w = fmaxf(q0.w + q1.w + c1.w, 0.f);
        }
        const float* bp = W + (long)(k0 + brow) * ldw + col0 + bcol;
        b0 = *(const float4*)bp;
        b1 = *(const float4*)(bp + 4);
    };

    float acc[4][4] = {};
    LOAD(kbeg);
    const int NIT = (kend - kbeg) >> 5;
    for (int it = 0; it < NIT; ++it) {
        __syncthreads();
        As[aseg + 0][arow] = a0.x; As[aseg + 1][arow] = a0.y;
        As[aseg + 2][arow] = a0.z; As[aseg + 3][arow] = a0.w;
        As[aseg + 4][arow] = a1.x; As[aseg + 5][arow] = a1.y;
        As[aseg + 6][arow] = a1.z; As[aseg + 7][arow] = a1.w;
        *(float4*)&Bs[brow][bcol]     = b0;
        *(float4*)&Bs[brow][bcol + 4] = b1;
        __syncthreads();
        if (it + 1 < NIT) LOAD(kbeg + ((it + 1) << 5));
#pragma unroll
        for (int kk = 0; kk < 32; ++kk) {
            float4 av = *(const float4*)&As[kk][tr];
            float4 bv = *(const float4*)&Bs[kk][tc];
            acc[0][0] = fmaf(av.x, bv.x, acc[0][0]); acc[0][1] = fmaf(av.x, bv.y, acc[0][1]);
            acc[0][2] = fmaf(av.x, bv.z, acc[0][2]); acc[0][3] = fmaf(av.x, bv.w, acc[0][3]);
            acc[1][0] = fmaf(av.y, bv.x, acc[1][0]); acc[1][1] = fmaf(av.y, bv.y, acc[1][1]);
            acc[1][2] = fmaf(av.y, bv.z, acc[1][2]); acc[1][3] = fmaf(av.y, bv.w, acc[1][3]);
            acc[2][0] = fmaf(av.z, bv.x, acc[2][0]); acc[2][1] = fmaf(av.z, bv.y, acc[2][1]);
            acc[2][2] = fmaf(av.z, bv.z, acc[2][2]); acc[2][3] = fmaf(av.z, bv.w, acc[2][3]);
            acc[3][0] = fmaf(av.w, bv.x, acc[3][0]); acc[3][1] = fmaf(av.w, bv.y, acc[3][1]);
            acc[3][2] = fmaf(av.w, bv.z, acc[3][2]); acc[3][3] = fmaf(av.w, bv.w, acc[3][3]);
        }
    }

#pragma unroll
    for (int i = 0; i < 4; ++i)
        *(float4*)(C + (long)(row0 + tr + i) * ldc + col0 + tc) =
            make_float4(acc[i][0], acc[i][1], acc[i][2], acc[i][3]);
}

// ---------------------------------------------------------------------------
// step_gemms<LVL>: flat-grid co-launch (768 blocks, 3/CU).
//  LVL 0: bid<512 -> h1 partials (m1@Wm, split-K2) ; else gm cols [0,1024)
//  LVL 1: bid<512 -> h2 partials (relu(hP0+hP1+bm)@Wm, split-K2)
//                    ; else gm cols [1024,2048)
// ---------------------------------------------------------------------------
template<int LVL>
__global__ __launch_bounds__(256)
void step_gemms(const float* __restrict__ m1, const float* __restrict__ Wm,
                const float* __restrict__ bm,
                float* __restrict__ hP, float* __restrict__ h2P,
                const float* __restrict__ tm, const float* __restrict__ Wmg,
                float* __restrict__ gm)
{
    __shared__ float As[32][68];
    __shared__ float Bs[32][68];
    const int bid = blockIdx.x;
    if (bid < 512) {
        int x = bid & 15, y = (bid >> 4) & 15, kc = bid >> 8;
        if (LVL == 0)
            gemm64_core<0>(m1, 1024, 0, nullptr, Wm, 1024,
                           hP + (long)kc * 1048576, 1024,
                           y * 64, x * 64, kc * 512, kc * 512 + 512, As, Bs);
        else
            gemm64_core<1>(hP, 1024, 1048576, bm, Wm, 1024,
                           h2P + (long)kc * 1048576, 1024,
                           y * 64, x * 64, kc * 512, kc * 512 + 512, As, Bs);
    } else {
        int j = bid - 512;
        int x = (j & 15) + (LVL == 0 ? 0 : 16);
        int y = (j >> 4) & 1, s = j >> 5;
        gemm64_core<0>(tm + s * 1024, 8192, 0, nullptr,
                       Wmg + (long)s * 2097152, 2048,
                       gm + s * 2048, 16384,
                       y * 64, x * 64, 0, 1024, As, Bs);
    }
}

// ---------------------------------------------------------------------------
// block reduction (256 threads) of (sum, sumsq); safe for repeated use
// ---------------------------------------------------------------------------
__device__ inline void block_reduce2(float& s1, float& s2)
{
    __shared__ float red[2][4];
    __syncthreads();
#pragma unroll
    for (int off = 32; off > 0; off >>= 1) {
        s1 += __shfl_down(s1, off, 64);
        s2 += __shfl_down(s2, off, 64);
    }
    int tid = threadIdx.x;
    if ((tid & 63) == 0) { red[0][tid >> 6] = s1; red[1][tid >> 6] = s2; }
    __syncthreads();
    s1 = red[0][0] + red[0][1] + red[0][2] + red[0][3];
    s2 = red[1][0] + red[1][1] + red[1][2] + red[1][3];
}

// ---------------------------------------------------------------------------
// ln1 (t=0): m1 = LN(mem0 + v[:,0])*g+b ; tm = tanh(mem0)
// ---------------------------------------------------------------------------
__global__ __launch_bounds__(256)
void ln1_kern(const float* __restrict__ memprev, const float* __restrict__ v,
              const float* __restrict__ g, const float* __restrict__ bb,
              float* __restrict__ m1, float* __restrict__ tm)
{
    const int row = blockIdx.x;
    const int b   = row >> 3;
    const int d   = threadIdx.x << 2;

    float4 mv = *(const float4*)(memprev + (long)row * DMEM + d);
    float4 vv = *(const float4*)(v + ((long)b * NT) * DMEM + d);

    *(float4*)(tm + (long)row * DMEM + d) =
        make_float4(tanhf(mv.x), tanhf(mv.y), tanhf(mv.z), tanhf(mv.w));

    float x0 = mv.x + vv.x, x1 = mv.y + vv.y, x2 = mv.z + vv.z, x3 = mv.w + vv.w;
    float s1 = x0 + x1 + x2 + x3;
    float s2 = x0 * x0 + x1 * x1 + x2 * x2 + x3 * x3;
    block_reduce2(s1, s2);
    float mean = s1 * (1.f / 1024.f);
    float var  = s2 * (1.f / 1024.f) - mean * mean;
    float inv  = 1.f / sqrtf(var + 1e-5f);

    float4 gg = *(const float4*)&g[d];
    float4 bv = *(const float4*)&bb[d];
    *(float4*)(m1 + (long)row * DMEM + d) =
        make_float4((x0 - mean) * inv * gg.x + bv.x,
                    (x1 - mean) * inv * gg.y + bv.y,
                    (x2 - mean) * inv * gg.z + bv.z,
                    (x3 - mean) * inv * gg.w + bv.w);
}

// ---------------------------------------------------------------------------
// tail row: h2=relu(h2P0+h2P1+bm); t2=tanh(LN2(m1+h2));
// out = sig(gm+gi+ib)*t2 + sig(gm'+gi'+fb)*mem;
// if !last: tm=tanh(out); m1'=LN1(out+v[:,t+1]);  if last: also final_mem.
// (logic hardware-validated in r10's passing run)
// ---------------------------------------------------------------------------
__device__ __forceinline__ void tail_row(
    int row, int t, const float* __restrict__ m1in,
    const float* __restrict__ h2P, const float* __restrict__ bm,
    const float* __restrict__ g2, const float* __restrict__ b2,
    const float* __restrict__ gm, const float* __restrict__ gi,
    const float* __restrict__ memprev, float fb, float ib,
    const float* __restrict__ v,
    const float* __restrict__ g1, const float* __restrict__ b1,
    float* __restrict__ outp, float* m1out, float* __restrict__ tm,
    int last, float* __restrict__ outFinal)
{
    const int b = row >> 3;
    const int d = threadIdx.x << 2;
    const long o = (long)row * DMEM + d;

    float4 a  = *(const float4*)(m1in + o);
    float4 q0 = *(const float4*)(h2P + o);
    float4 q1 = *(const float4*)(h2P + 1048576 + o);
    float4 bb = *(const float4*)&bm[d];
    float x0 = a.x + fmaxf(q0.x + q1.x + bb.x, 0.f);
    float x1 = a.y + fmaxf(q0.y + q1.y + bb.y, 0.f);
    float x2 = a.z + fmaxf(q0.z + q1.z + bb.z, 0.f);
    float x3 = a.w + fmaxf(q0.w + q1.w + bb.w, 0.f);

    float s1 = x0 + x1 + x2 + x3;
    float s2 = x0 * x0 + x1 * x1 + x2 * x2 + x3 * x3;
    block_reduce2(s1, s2);
    float mean = s1 * (1.f / 1024.f);
    float var  = s2 * (1.f / 1024.f) - mean * mean;
    float inv  = 1.f / sqrtf(var + 1e-5f);

    float4 gg  = *(const float4*)&g2[d];
    float4 b2v = *(const float4*)&b2[d];
    float t20 = tanhf((x0 - mean) * inv * gg.x + b2v.x);
    float t21 = tanhf((x1 - mean) * inv * gg.y + b2v.y);
    float t22 = tanhf((x2 - mean) * inv * gg.z + b2v.z);
    float t23 = tanhf((x3 - mean) * inv * gg.w + b2v.w);

    const long go = (long)row * NGATES + d;
    float4 ge0 = *(const float4*)(gm + go);
    float4 ge1 = *(const float4*)(gm + go + DMEM);
    const long io = ((long)b * NT + t) * NGATES + d;
    float4 i0 = *(const float4*)(gi + io);
    float4 i1 = *(const float4*)(gi + io + DMEM);
    float4 mv = *(const float4*)(memprev + o);

    float4 ov;
    ov.x = sigm(ge0.x + i0.x + ib) * t20 + sigm(ge1.x + i1.x + fb) * mv.x;
    ov.y = sigm(ge0.y + i0.y + ib) * t21 + sigm(ge1.y + i1.y + fb) * mv.y;
    ov.z = sigm(ge0.z + i0.z + ib) * t22 + sigm(ge1.z + i1.z + fb) * mv.z;
    ov.w = sigm(ge0.w + i0.w + ib) * t23 + sigm(ge1.w + i1.w + fb) * mv.w;
    *(float4*)(outp + o) = ov;

    if (!last) {
        float4 vv = *(const float4*)(v + ((long)b * NT + t + 1) * DMEM + d);
        *(float4*)(tm + o) =
            make_float4(tanhf(ov.x), tanhf(ov.y), tanhf(ov.z), tanhf(ov.w));

        float y0 = ov.x + vv.x, y1 = ov.y + vv.y;
        float y2 = ov.z + vv.z, y3 = ov.w + vv.w;
        float u1 = y0 + y1 + y2 + y3;
        float u2 = y0 * y0 + y1 * y1 + y2 * y2 + y3 * y3;
        block_reduce2(u1, u2);
        float mean1 = u1 * (1.f / 1024.f);
        float var1  = u2 * (1.f / 1024.f) - mean1 * mean1;
        float inv1  = 1.f / sqrtf(var1 + 1e-5f);

        float4 g1v = *(const float4*)&g1[d];
        float4 b1v = *(const float4*)&b1[d];
        *(float4*)(m1out + o) =
            make_float4((y0 - mean1) * inv1 * g1v.x + b1v.x,
                        (y1 - mean1) * inv1 * g1v.y + b1v.y,
                        (y2 - mean1) * inv1 * g1v.z + b1v.z,
                        (y3 - mean1) * inv1 * g1v.w + b1v.w);
    } else {
        *(float4*)(outFinal + o) = ov;   // final_mem = outs[31]
    }
}

__global__ __launch_bounds__(256)
void step_fused(const float* m1in, const float* __restrict__ h2P,
                const float* __restrict__ bm,
                const float* __restrict__ g2, const float* __restrict__ b2,
                const float* __restrict__ gm, const float* __restrict__ gi, int t,
                const float* __restrict__ memprev,
                const float* __restrict__ fbp, const float* __restrict__ ibp,
                const float* __restrict__ v,
                const float* __restrict__ g1, const float* __restrict__ b1,
                float* __restrict__ outp, float* m1out,
                float* __restrict__ tm, int last, float* __restrict__ outFinal)
{
    tail_row(blockIdx.x, t, m1in, h2P, bm, g2, b2, gm, gi, memprev,
             *fbp, *ibp, v, g1, b1, outp, m1out, tm, last, outFinal);
}

// ---------------------------------------------------------------------------
extern "C" void kernel_launch(void* const* d_in, const int* in_sizes, int n_in,
                              void* d_out, int out_size, void* d_ws, size_t ws_size,
                              hipStream_t stream)
{
    const float* x    = (const float*)d_in[0];
    const float* mem0 = (const float*)d_in[1];
    const float* Wi   = (const float*)d_in[2];
    const float* bi   = (const float*)d_in[3];
    // d_in[4..7] = Wq,bq,Wk,bk : dead (softmax over singleton axis == 1)
    const float* Wv   = (const float*)d_in[8];
    const float* bv   = (const float*)d_in[9];
    const float* Wm   = (const float*)d_in[10];
    const float* bm   = (const float*)d_in[11];
    const float* ln1g = (const float*)d_in[12];
    const float* ln1b = (const float*)d_in[13];
    const float* ln2g = (const float*)d_in[14];
    const float* ln2b = (const float*)d_in[15];
    const float* repw = (const float*)d_in[16];
    const float* Wg   = (const float*)d_in[17];
    const float* bg   = (const float*)d_in[18];
    const float* Wmg  = (const float*)d_in[19];
    const float* fbp  = (const float*)d_in[20];
    const float* ibp  = (const float*)d_in[21];

    float* out = (float*)d_out;
    char*  ws  = (char*)d_ws;
    const long MB = 1024L * 1024L;

    // persistent across scan
    float* v    = (float*)(ws + 0 * MB);   // 16 MB [4096][1024]
    float* gi   = (float*)(ws + 16 * MB);  // 32 MB [4096][2048]
    // phase-A transient (folded inside vgi_kern's A-staging)
    float* inpP = (float*)(ws + 48 * MB);  // 32 MB [2][4096][1024]
    // per-step
    float* m1   = (float*)(ws + 48 * MB);  //  4 MB
    float* tm   = (float*)(ws + 52 * MB);  //  4 MB
    float* hP   = (float*)(ws + 56 * MB);  //  8 MB [2][1024][1024]
    float* gm   = (float*)(ws + 64 * MB);  //  8 MB [128][8][2048]
    float* h2P  = (float*)(ws + 72 * MB);  //  8 MB [2][1024][1024]
    // peak exactly 80 MB

    dim3 blk(256);

    // ---- phase A ----
    gemm_inp<<<512, blk, 0, stream>>>(x, Wi, inpP);
    vgi_kern<<<768, blk, 0, stream>>>(inpP, bi, repw, Wv, bv, v, Wg, bg, gi);

    // ---- t=0 LN1 + tanh(mem0) ----
    ln1_kern<<<1024, blk, 0, stream>>>(mem0, v, ln1g, ln1b, m1, tm);

    // ---- recurrent scan (proven r8 structure; final_mem written in tail) ----
    for (int t = 0; t < NT; ++t) {
        const float* memprev = (t == 0) ? mem0 : out + (long)(t - 1) * STEPN;
        step_gemms<0><<<768, blk, 0, stream>>>(m1, Wm, bm, hP, h2P, tm, Wmg, gm);
        step_gemms<1><<<768, blk, 0, stream>>>(m1, Wm, bm, hP, h2P, tm, Wmg, gm);
        step_fused<<<1024, blk, 0, stream>>>(
            m1, h2P, bm, ln2g, ln2b, gm, gi, t, memprev, fbp, ibp,
            v, ln1g, ln1b, out + (long)t * STEPN, m1, tm,
            (t == NT - 1) ? 1 : 0, out + (long)NT * STEPN);
    }
}